// Round 3
// baseline (958.382 us; speedup 1.0000x reference)
//
#include <hip/hip_runtime.h>
#include <hip/hip_bf16.h>

#define D 1024
#define H 8
#define S 2048
#define DFF 3072
#define HD 8192
#define EPS 1e-5f
#define HB 4   // heads per attention pass (SC buffer = HB * 8 MB)

typedef __attribute__((ext_vector_type(8))) short short8;   // 8 bf16 in 4 VGPRs
typedef __attribute__((ext_vector_type(4))) float float4v;  // MFMA acc
typedef __attribute__((ext_vector_type(8))) unsigned short u16x8;

// GEMM flags
#define F_OUT_BF16 1
#define F_ACCUM    2   // fp32 atomicAdd into C
#define F_RELU     4
#define F_BIAS_COL 8
#define F_BIAS_ROW 16
#define F_SPLITK   32  // bias applied only when kz == 0

__device__ __forceinline__ void async16(void* lds, const void* g) {
    __builtin_amdgcn_global_load_lds(
        (const __attribute__((address_space(1))) unsigned int*)g,
        (__attribute__((address_space(3))) unsigned int*)lds, 16, 0, 0);
}

// ---------------------------------------------------------------------------
// C = alpha*A.Bt^T (+bias)(+relu).  A:[M,K] bf16 lda; Bt:[N,K] bf16 ldb.
// blockIdx.z = z2 * kSplit + kz: z2 batches (strides sA/sB/sC/sBias), kz
// splits K (A,B advance kz*K elems along the row; C accumulated atomically).
// Requires grid tiles: (nm*nn)%8==0 and nn%4==0 (XCD swizzle).
// ---------------------------------------------------------------------------
__global__ __launch_bounds__(256) void gemm_bt(
    const __hip_bfloat16* __restrict__ A,
    const __hip_bfloat16* __restrict__ Bt,
    void* __restrict__ Cout,
    const float* __restrict__ bias,
    int M, int N, int K,
    int lda, int ldb, int ldc,
    long sA, long sB, long sC, int sBias,
    int kSplit, float alpha, int flags)
{
    __shared__ __align__(16) __hip_bfloat16 As[128 * 32];
    __shared__ __align__(16) __hip_bfloat16 Bs[128 * 32];

    const int z  = blockIdx.z;
    const int z2 = z / kSplit;
    const int kz = z - z2 * kSplit;
    A  += (long)z2 * sA + (long)kz * K;
    Bt += (long)z2 * sB + (long)kz * K;
    const bool bon = bias && (!(flags & F_SPLITK) || kz == 0);
    const float* bp = bon ? bias + (long)z2 * sBias : nullptr;

    // XCD-aware tile swizzle: blocks i -> XCD i%8; give each XCD a contiguous
    // tile range, then band-map (4 cols wide) for a square-ish L2 working set.
    const int nn = gridDim.x, nm = gridDim.y;
    const int tot = nm * nn;
    const int pid = blockIdx.y * nn + blockIdx.x;
    const int lin = (pid & 7) * (tot >> 3) + (pid >> 3);
    const int bandh = nm << 2;
    const int band = lin / bandh;
    const int rr = lin - band * bandh;
    const int m0 = (rr >> 2) * 128;
    const int n0 = (band * 4 + (rr & 3)) * 128;

    const int t    = threadIdx.x;
    const int wave = t >> 6;
    const int lane = t & 63;
    const int lr   = lane & 15;     // row within 16x16 fragment
    const int lq   = lane >> 4;     // k-quad
    const int lqx  = lq ^ ((lr >> 1) & 3);   // LDS bank de-conflict xor
    const int wm   = (wave >> 1) * 64;
    const int wn   = (wave & 1) * 64;

    // staging: tile = 128 rows x 4 chunks(16B); thread t owns LDS slots t,
    // t+256 (lane-contiguous dest required by global_load_lds). The XOR
    // swizzle is applied on the SOURCE side: slot t holds global chunk
    // (row=t>>2, kc=(t&3)^((row>>1)&3)).
    const int srow = t >> 2;
    const int skc  = (t & 3) ^ ((t >> 3) & 3);
    const __hip_bfloat16* Ap1 = A  + (long)(m0 + srow) * lda + skc * 8;
    const __hip_bfloat16* Ap2 = Ap1 + 64L * lda;
    const __hip_bfloat16* Bp1 = Bt + (long)(n0 + srow) * ldb + skc * 8;
    const __hip_bfloat16* Bp2 = Bp1 + 64L * ldb;
    uint4* dA1 = (uint4*)As + t;
    uint4* dA2 = (uint4*)As + t + 256;
    uint4* dB1 = (uint4*)Bs + t;
    uint4* dB2 = (uint4*)Bs + t + 256;

    float4v acc[4][4];
    const float4v vzero = {0.f, 0.f, 0.f, 0.f};
    #pragma unroll
    for (int i = 0; i < 4; i++)
        #pragma unroll
        for (int j = 0; j < 4; j++) acc[i][j] = vzero;

    for (int k0 = 0; k0 < K; k0 += 32) {
        __syncthreads();            // prev iter's ds_reads complete
        async16(dA1, Ap1);
        async16(dA2, Ap2);
        async16(dB1, Bp1);
        async16(dB2, Bp2);
        Ap1 += 32; Ap2 += 32; Bp1 += 32; Bp2 += 32;
        __syncthreads();            // vmcnt(0) drain: tiles ready

        short8 af[4], bf[4];
        #pragma unroll
        for (int i = 0; i < 4; i++)
            af[i] = *(const short8*)&As[(wm + i * 16 + lr) * 32 + lqx * 8];
        #pragma unroll
        for (int i = 0; i < 4; i++)
            bf[i] = *(const short8*)&Bs[(wn + i * 16 + lr) * 32 + lqx * 8];

        #pragma unroll
        for (int mi = 0; mi < 4; mi++)
            #pragma unroll
            for (int ni = 0; ni < 4; ni++)
                acc[mi][ni] = __builtin_amdgcn_mfma_f32_16x16x32_bf16(
                    af[mi], bf[ni], acc[mi][ni], 0, 0, 0);
    }

    __hip_bfloat16* Cb = (__hip_bfloat16*)Cout + (long)z2 * sC;
    float*          Cf = (float*)Cout + (long)z2 * sC;

    // epilogue: lane, reg r -> row = 4*lq + r, col = lr (within 16x16 tile)
    #pragma unroll
    for (int mi = 0; mi < 4; mi++) {
        #pragma unroll
        for (int r = 0; r < 4; r++) {
            const int row = m0 + wm + mi * 16 + lq * 4 + r;
            const float brow = (bon && (flags & F_BIAS_ROW)) ? bp[row] : 0.f;
            #pragma unroll
            for (int ni = 0; ni < 4; ni++) {
                const int col = n0 + wn + ni * 16 + lr;
                float v = acc[mi][ni][r] * alpha + brow;
                if (bon && (flags & F_BIAS_COL)) v += bp[col];
                if (flags & F_RELU) v = fmaxf(v, 0.f);
                const long idx = (long)row * ldc + col;
                if (flags & F_OUT_BF16) {
                    Cb[idx] = __float2bfloat16(v);
                } else if (flags & F_ACCUM) {
                    atomicAdd(&Cf[idx], v);
                } else {
                    Cf[idx] = v;
                }
            }
        }
    }
}

// ---------------------------------------------------------------------------
// fp32 [R,C] -> bf16 [C,R] transpose+cast, batched via blockIdx.z
// ---------------------------------------------------------------------------
__global__ __launch_bounds__(256) void transpose_cast(
    const float* __restrict__ in, __hip_bfloat16* __restrict__ out, int R, int C)
{
    __shared__ float tile[32][33];
    const long boff = (long)blockIdx.z * R * C;
    const int c0 = blockIdx.x * 32, r0 = blockIdx.y * 32;
    const int tx = threadIdx.x & 31, ty = threadIdx.x >> 5;
    #pragma unroll
    for (int i = ty; i < 32; i += 8)
        tile[i][tx] = in[boff + (long)(r0 + i) * C + c0 + tx];
    __syncthreads();
    #pragma unroll
    for (int i = ty; i < 32; i += 8)
        out[boff + (long)(c0 + i) * R + r0 + tx] = __float2bfloat16(tile[tx][i]);
}

// concat two float vectors of length HD into one of length 2*HD
__global__ __launch_bounds__(256) void concat_bias(
    const float* __restrict__ a, const float* __restrict__ b,
    float* __restrict__ o)
{
    const int i = blockIdx.x * 256 + threadIdx.x;
    o[i] = (i < HD) ? a[i] : b[i - HD];
}

// ---------------------------------------------------------------------------
// x = emb[tokens] + sinusoidal PE ; writes fp32 and bf16 copies
// ---------------------------------------------------------------------------
__global__ __launch_bounds__(256) void embed_pos(
    const int* __restrict__ tokens, const float* __restrict__ emb,
    float* __restrict__ xf, __hip_bfloat16* __restrict__ xb)
{
    const int s = blockIdx.x;
    const int tok = tokens[s];
    for (int d = threadIdx.x; d < D; d += 256) {
        const float e = emb[(long)tok * D + d];
        const float expo = (float)((d >> 1) << 1) / (float)D;
        const float angle = (float)s * powf(10000.f, -expo);
        const float pe = (d & 1) ? cosf(angle) : sinf(angle);
        const float v = e + pe;
        xf[(long)s * D + d] = v;
        xb[(long)s * D + d] = __float2bfloat16(v);
    }
}

// ---------------------------------------------------------------------------
// in-place row softmax over bf16 [rows, S]; one block per row (vectorized)
// ---------------------------------------------------------------------------
__global__ __launch_bounds__(256) void softmax_rows(__hip_bfloat16* __restrict__ Sc)
{
    __hip_bfloat16* p = Sc + (long)blockIdx.x * S;
    const int t = threadIdx.x;
    const int wave = t >> 6, lane = t & 63;
    __shared__ float wred[4], wsum[4];

    u16x8 u = ((const u16x8*)p)[t];
    float v[8];
    float mx = -1e30f;
    #pragma unroll
    for (int j = 0; j < 8; j++) {
        const unsigned int b = ((unsigned int)u[j]) << 16;
        v[j] = __builtin_bit_cast(float, b);
        mx = fmaxf(mx, v[j]);
    }
    #pragma unroll
    for (int off = 32; off; off >>= 1) mx = fmaxf(mx, __shfl_down(mx, off));
    if (lane == 0) wred[wave] = mx;
    __syncthreads();
    mx = fmaxf(fmaxf(wred[0], wred[1]), fmaxf(wred[2], wred[3]));

    float sum = 0.f;
    #pragma unroll
    for (int j = 0; j < 8; j++) { v[j] = expf(v[j] - mx); sum += v[j]; }
    #pragma unroll
    for (int off = 32; off; off >>= 1) sum += __shfl_down(sum, off);
    if (lane == 0) wsum[wave] = sum;
    __syncthreads();
    sum = wsum[0] + wsum[1] + wsum[2] + wsum[3];

    const float inv = 1.f / sum;
    u16x8 o;
    #pragma unroll
    for (int j = 0; j < 8; j++) {
        const __hip_bfloat16 h = __float2bfloat16(v[j] * inv);
        o[j] = __builtin_bit_cast(unsigned short, h);
    }
    ((u16x8*)p)[t] = o;
}

// ---------------------------------------------------------------------------
// z = mha + x ; accumulate global sum & sumsq into stats[0..1] (pre-zeroed)
// ---------------------------------------------------------------------------
__global__ __launch_bounds__(256) void residual_stats(
    const float* __restrict__ mha, const float* __restrict__ xf,
    float* __restrict__ z, float* __restrict__ stats)
{
    const long i0 = (long)blockIdx.x * 2048 + threadIdx.x;
    float s = 0.f, s2 = 0.f;
    #pragma unroll
    for (int j = 0; j < 8; j++) {
        const long i = i0 + j * 256;
        const float v = mha[i] + xf[i];
        z[i] = v;
        s += v; s2 += v * v;
    }
    #pragma unroll
    for (int off = 32; off; off >>= 1) { s += __shfl_down(s, off); s2 += __shfl_down(s2, off); }
    const int wave = threadIdx.x >> 6, lane = threadIdx.x & 63;
    __shared__ float ws1[4], ws2[4];
    if (lane == 0) { ws1[wave] = s; ws2[wave] = s2; }
    __syncthreads();
    if (threadIdx.x == 0) {
        atomicAdd(&stats[0], ws1[0] + ws1[1] + ws1[2] + ws1[3]);
        atomicAdd(&stats[1], ws2[0] + ws2[1] + ws2[2] + ws2[3]);
    }
}

// zn = (z - mean) * rsqrt(var + eps), cast to bf16
__global__ __launch_bounds__(256) void ln_cast(
    const float* __restrict__ z, const float* __restrict__ stats,
    __hip_bfloat16* __restrict__ zn)
{
    const float invN = 1.f / (float)(S * D);
    const float mean = stats[0] * invN;
    const float var  = stats[1] * invN - mean * mean;
    const float rs   = rsqrtf(var + EPS);
    const long i0 = (long)blockIdx.x * 2048 + threadIdx.x;
    #pragma unroll
    for (int j = 0; j < 8; j++) {
        const long i = i0 + j * 256;
        zn[i] = __float2bfloat16((z[i] - mean) * rs);
    }
}

// ---------------------------------------------------------------------------
extern "C" void kernel_launch(void* const* d_in, const int* in_sizes, int n_in,
                              void* d_out, int out_size, void* d_ws, size_t ws_size,
                              hipStream_t stream)
{
    const int*   tokens = (const int*)  d_in[0];
    const float* emb    = (const float*)d_in[1];
    const float* Wq     = (const float*)d_in[2];
    const float* bq     = (const float*)d_in[3];
    const float* Wk     = (const float*)d_in[4];
    const float* bk     = (const float*)d_in[5];
    const float* Wv     = (const float*)d_in[6];
    const float* bv     = (const float*)d_in[7];
    const float* W1     = (const float*)d_in[8];
    const float* b1     = (const float*)d_in[9];
    const float* W2     = (const float*)d_in[10];
    const float* b2     = (const float*)d_in[11];
    float* out = (float*)d_out;

    char* w = (char*)d_ws;
    const long MB = 1 << 20;
    // layout with aliasing:
    //  0: XB(4) | 4: XF(8) | 12: WQT(16) WKT@28(16) WVT@44(16)
    //  after QK gemm: SC@12(32) ; after VT gemm: MHA@44(8,f32) Z@52(8,f32)
    //  60: W1T(6) | 66: W2T(6) | 72: QK(64) -> after attn: ZN@72(4) FFH@76(12)
    //  136: VT(32) | 168: STATS | 168+4K: BQK(64K)
    __hip_bfloat16* XB  = (__hip_bfloat16*)(w + 0 * MB);
    float*          XF  = (float*)(w + 4 * MB);
    __hip_bfloat16* WQT = (__hip_bfloat16*)(w + 12 * MB);   // contiguous with WKT
    __hip_bfloat16* WKT = (__hip_bfloat16*)(w + 28 * MB);
    __hip_bfloat16* WVT = (__hip_bfloat16*)(w + 44 * MB);
    __hip_bfloat16* SC  = (__hip_bfloat16*)(w + 12 * MB);   // alias WQT/WKT
    float*          MHA = (float*)(w + 44 * MB);            // alias WVT
    float*          Z   = (float*)(w + 52 * MB);            // alias WVT tail
    __hip_bfloat16* W1T = (__hip_bfloat16*)(w + 60 * MB);
    __hip_bfloat16* W2T = (__hip_bfloat16*)(w + 66 * MB);
    __hip_bfloat16* QK  = (__hip_bfloat16*)(w + 72 * MB);   // [S, 2*HD]
    __hip_bfloat16* ZN  = (__hip_bfloat16*)(w + 72 * MB);   // alias QK (dead)
    __hip_bfloat16* FFH = (__hip_bfloat16*)(w + 76 * MB);   // alias QK (dead)
    __hip_bfloat16* VT  = (__hip_bfloat16*)(w + 136 * MB);
    float*          STATS = (float*)(w + 168 * MB);
    float*          BQK   = (float*)(w + 168 * MB + 4096);  // bq || bk

    hipMemsetAsync(STATS, 0, 256, stream);

    embed_pos<<<S, 256, 0, stream>>>(tokens, emb, XF, XB);

    // weight transpose+cast
    transpose_cast<<<dim3(32, 32, H), 256, 0, stream>>>(Wq, WQT, D, D);
    transpose_cast<<<dim3(32, 32, H), 256, 0, stream>>>(Wk, WKT, D, D);
    transpose_cast<<<dim3(32, 32, H), 256, 0, stream>>>(Wv, WVT, D, D);
    transpose_cast<<<dim3(96, 32, 1), 256, 0, stream>>>(W1, W1T, D, DFF);  // -> [DFF,D]
    transpose_cast<<<dim3(32, 96, 1), 256, 0, stream>>>(W2, W2T, DFF, D);  // -> [D,DFF]
    concat_bias<<<2 * HD / 256, 256, 0, stream>>>(bq, bk, BQK);

    // Q||K = x @ [Wq;Wk]^T + [bq;bk]   [S, 16384], one dispatch, 8 blk/CU
    gemm_bt<<<dim3(2 * HD / 128, S / 128), 256, 0, stream>>>(
        XB, WQT, QK, BQK, S, 2 * HD, D, D, D, 2 * HD,
        0, 0, 0, 0, 1, 1.f, F_OUT_BF16 | F_BIAS_COL);
    // VT[h] = Wv[h]^T @ x^T + bv[h]   [H][D, S]
    gemm_bt<<<dim3(S / 128, D / 128, H), 256, 0, stream>>>(
        WVT, XB, VT, bv, D, S, D, D, D, S,
        (long)D * D, 0, (long)D * S, D, 1, 1.f,
        F_OUT_BF16 | F_BIAS_ROW);

    // MHA accumulator (zero AFTER VT gemm: aliases WVT)
    hipMemsetAsync(MHA, 0, (size_t)S * D * sizeof(float), stream);

    const float inv_sqrt_d = 0.03125f;  // 1/sqrt(1024)

    for (int g = 0; g < H / HB; g++) {
        // scores[z] = Q_h K_h^T / sqrt(D), h = g*HB+z   [S,S] bf16
        gemm_bt<<<dim3(S / 128, S / 128, HB), 256, 0, stream>>>(
            QK + (long)g * HB * D, QK + HD + (long)g * HB * D, SC,
            (const float*)nullptr, S, S, D, 2 * HD, 2 * HD, S,
            D, D, (long)S * S, 0, 1, inv_sqrt_d, F_OUT_BF16);
        softmax_rows<<<HB * S, 256, 0, stream>>>(SC);
        // MHA += P_h @ V_h   split-K=2, fp32 atomic accumulate
        gemm_bt<<<dim3(D / 128, S / 128, HB * 2), 256, 0, stream>>>(
            SC, VT + (long)g * HB * D * S, MHA,
            (const float*)nullptr, S, D, S / 2, S, S, D,
            (long)S * S, (long)D * S, 0, 0, 2, 1.f, F_ACCUM);
    }

    residual_stats<<<(S * D) / 2048, 256, 0, stream>>>(MHA, XF, Z, STATS);
    ln_cast<<<(S * D) / 2048, 256, 0, stream>>>(Z, STATS, ZN);

    // FF1: relu(zn @ W1 + b1)  [S,DFF] bf16
    gemm_bt<<<dim3(DFF / 128, S / 128), 256, 0, stream>>>(
        ZN, W1T, FFH, b1, S, DFF, D, D, D, DFF,
        0, 0, 0, 0, 1, 1.f, F_OUT_BF16 | F_BIAS_COL | F_RELU);
    // FF2: out = h @ W2 + b2  split-K=4, fp32 atomic into zeroed d_out
    hipMemsetAsync(out, 0, (size_t)S * D * sizeof(float), stream);
    gemm_bt<<<dim3(D / 128, S / 128, 4), 256, 0, stream>>>(
        FFH, W2T, out, b2, S, D, DFF / 4, DFF, DFF, D,
        0, 0, 0, 0, 4, 1.f, F_ACCUM | F_BIAS_COL | F_SPLITK);
}

// Round 4
// 772.458 us; speedup vs baseline: 1.2407x; 1.2407x over previous
//
#include <hip/hip_runtime.h>
#include <hip/hip_bf16.h>

#define D 1024
#define H 8
#define S 2048
#define DFF 3072
#define HD 8192
#define EPS 1e-5f

typedef __attribute__((ext_vector_type(8))) short short8;   // 8 bf16 in 4 VGPRs
typedef __attribute__((ext_vector_type(4))) float float4v;  // MFMA acc
typedef __attribute__((ext_vector_type(8))) unsigned short u16x8;

// GEMM flags
#define F_OUT_BF16 1
#define F_RELU     4
#define F_BIAS_COL 8
#define F_BIAS_ROW 16

__device__ __forceinline__ void async16(void* lds, const void* g) {
    __builtin_amdgcn_global_load_lds(
        (const __attribute__((address_space(1))) unsigned int*)g,
        (__attribute__((address_space(3))) unsigned int*)lds, 16, 0, 0);
}

// ---------------------------------------------------------------------------
// C = alpha * A.Bt^T (+bias)(+relu).  A:[M,K] bf16 lda; Bt:[N,K] bf16 ldb.
// blockIdx.z = z2 * kSplit + kz:
//   z2 batches with strides sA/sB/sC/sBias;
//   kz K-splits with strides sAz/sBz/sCz (each kz writes its OWN C slice —
//   no atomics; reduce afterwards).
// Each block additionally loops nkb batch-K chunks (advance sAk/sBk between
// chunks), accumulating in registers — used to sum heads without atomics.
// Block 256 = 4 waves 2x2; wave does 64x64 via 4x4 mfma_16x16x32_bf16.
// ---------------------------------------------------------------------------
__global__ __launch_bounds__(256) void gemm_bt(
    const __hip_bfloat16* __restrict__ A,
    const __hip_bfloat16* __restrict__ Bt,
    void* __restrict__ Cout,
    const float* __restrict__ bias,
    int M, int N, int K,
    int lda, int ldb, int ldc,
    long sA, long sB, long sC, int sBias,
    int kSplit, long sAz, long sBz, long sCz,
    int nkb, long sAk, long sBk,
    float alpha, int flags)
{
    __shared__ __align__(16) __hip_bfloat16 As[128 * 32];
    __shared__ __align__(16) __hip_bfloat16 Bs[128 * 32];

    const int z  = blockIdx.z;
    const int z2 = z / kSplit;
    const int kz = z - z2 * kSplit;
    A  += (long)z2 * sA + (long)kz * sAz;
    Bt += (long)z2 * sB + (long)kz * sBz;
    const float* bp = bias ? bias + (long)z2 * sBias : nullptr;

    // XCD-aware tile swizzle: blocks i -> XCD i%8; give each XCD a contiguous
    // tile range, then band-map (4 cols wide) for a square-ish L2 working set.
    const int nn = gridDim.x, nm = gridDim.y;
    const int tot = nm * nn;
    const int pid = blockIdx.y * nn + blockIdx.x;
    const int lin = (pid & 7) * (tot >> 3) + (pid >> 3);
    const int bandh = nm << 2;
    const int band = lin / bandh;
    const int rr = lin - band * bandh;
    const int m0 = (rr >> 2) * 128;
    const int n0 = (band * 4 + (rr & 3)) * 128;

    const int t    = threadIdx.x;
    const int wave = t >> 6;
    const int lane = t & 63;
    const int lr   = lane & 15;     // row within 16x16 fragment
    const int lq   = lane >> 4;     // k-quad
    const int lqx  = lq ^ ((lr >> 1) & 3);   // LDS bank de-conflict xor
    const int wm   = (wave >> 1) * 64;
    const int wn   = (wave & 1) * 64;

    // staging: tile = 128 rows x 4 chunks(16B); thread t owns LDS slots t,
    // t+256 (lane-contiguous dest required by global_load_lds). XOR swizzle
    // applied on the SOURCE side: slot t holds chunk (row=t>>2, kc^((row>>1)&3)).
    const int srow = t >> 2;
    const int skc  = (t & 3) ^ ((t >> 3) & 3);
    const __hip_bfloat16* Ap1 = A  + (long)(m0 + srow) * lda + skc * 8;
    const __hip_bfloat16* Ap2 = Ap1 + 64L * lda;
    const __hip_bfloat16* Bp1 = Bt + (long)(n0 + srow) * ldb + skc * 8;
    const __hip_bfloat16* Bp2 = Bp1 + 64L * ldb;
    uint4* dA1 = (uint4*)As + t;
    uint4* dA2 = (uint4*)As + t + 256;
    uint4* dB1 = (uint4*)Bs + t;
    uint4* dB2 = (uint4*)Bs + t + 256;

    float4v acc[4][4];
    const float4v vzero = {0.f, 0.f, 0.f, 0.f};
    #pragma unroll
    for (int i = 0; i < 4; i++)
        #pragma unroll
        for (int j = 0; j < 4; j++) acc[i][j] = vzero;

    for (int kb = 0; kb < nkb; kb++) {
        for (int k0 = 0; k0 < K; k0 += 32) {
            __syncthreads();            // prev iter's ds_reads complete
            async16(dA1, Ap1);
            async16(dA2, Ap2);
            async16(dB1, Bp1);
            async16(dB2, Bp2);
            Ap1 += 32; Ap2 += 32; Bp1 += 32; Bp2 += 32;
            __syncthreads();            // vmcnt(0) drain: tiles ready

            short8 af[4], bf[4];
            #pragma unroll
            for (int i = 0; i < 4; i++)
                af[i] = *(const short8*)&As[(wm + i * 16 + lr) * 32 + lqx * 8];
            #pragma unroll
            for (int i = 0; i < 4; i++)
                bf[i] = *(const short8*)&Bs[(wn + i * 16 + lr) * 32 + lqx * 8];

            #pragma unroll
            for (int mi = 0; mi < 4; mi++)
                #pragma unroll
                for (int ni = 0; ni < 4; ni++)
                    acc[mi][ni] = __builtin_amdgcn_mfma_f32_16x16x32_bf16(
                        af[mi], bf[ni], acc[mi][ni], 0, 0, 0);
        }
        Ap1 += sAk - K; Ap2 += sAk - K;
        Bp1 += sBk - K; Bp2 += sBk - K;
    }

    __hip_bfloat16* Cb = (__hip_bfloat16*)Cout + (long)z2 * sC + (long)kz * sCz;
    float*          Cf = (float*)Cout          + (long)z2 * sC + (long)kz * sCz;

    // epilogue: lane, reg r -> row = 4*lq + r, col = lr (within 16x16 tile)
    #pragma unroll
    for (int mi = 0; mi < 4; mi++) {
        #pragma unroll
        for (int r = 0; r < 4; r++) {
            const int row = m0 + wm + mi * 16 + lq * 4 + r;
            const float brow = (bp && (flags & F_BIAS_ROW)) ? bp[row] : 0.f;
            #pragma unroll
            for (int ni = 0; ni < 4; ni++) {
                const int col = n0 + wn + ni * 16 + lr;
                float v = acc[mi][ni][r] * alpha + brow;
                if (bp && (flags & F_BIAS_COL)) v += bp[col];
                if (flags & F_RELU) v = fmaxf(v, 0.f);
                const long idx = (long)row * ldc + col;
                if (flags & F_OUT_BF16) Cb[idx] = __float2bfloat16(v);
                else                    Cf[idx] = v;
            }
        }
    }
}

// ---------------------------------------------------------------------------
// fp32 [R,C] -> bf16 [C,R] transpose+cast, batched via blockIdx.z
// ---------------------------------------------------------------------------
__global__ __launch_bounds__(256) void transpose_cast(
    const float* __restrict__ in, __hip_bfloat16* __restrict__ out, int R, int C)
{
    __shared__ float tile[32][33];
    const long boff = (long)blockIdx.z * R * C;
    const int c0 = blockIdx.x * 32, r0 = blockIdx.y * 32;
    const int tx = threadIdx.x & 31, ty = threadIdx.x >> 5;
    #pragma unroll
    for (int i = ty; i < 32; i += 8)
        tile[i][tx] = in[boff + (long)(r0 + i) * C + c0 + tx];
    __syncthreads();
    #pragma unroll
    for (int i = ty; i < 32; i += 8)
        out[boff + (long)(c0 + i) * R + r0 + tx] = __float2bfloat16(tile[tx][i]);
}

// concat two float vectors of length HD into one of length 2*HD
__global__ __launch_bounds__(256) void concat_bias(
    const float* __restrict__ a, const float* __restrict__ b,
    float* __restrict__ o)
{
    const int i = blockIdx.x * 256 + threadIdx.x;
    o[i] = (i < HD) ? a[i] : b[i - HD];
}

// ---------------------------------------------------------------------------
// x = emb[tokens] + sinusoidal PE ; writes fp32 and bf16 copies
// ---------------------------------------------------------------------------
__global__ __launch_bounds__(256) void embed_pos(
    const int* __restrict__ tokens, const float* __restrict__ emb,
    float* __restrict__ xf, __hip_bfloat16* __restrict__ xb)
{
    const int s = blockIdx.x;
    const int tok = tokens[s];
    for (int d = threadIdx.x; d < D; d += 256) {
        const float e = emb[(long)tok * D + d];
        const float expo = (float)((d >> 1) << 1) / (float)D;
        const float angle = (float)s * powf(10000.f, -expo);
        const float pe = (d & 1) ? cosf(angle) : sinf(angle);
        const float v = e + pe;
        xf[(long)s * D + d] = v;
        xb[(long)s * D + d] = __float2bfloat16(v);
    }
}

// ---------------------------------------------------------------------------
// in-place row softmax over bf16 [rows, S]; one block per row (vectorized)
// ---------------------------------------------------------------------------
__global__ __launch_bounds__(256) void softmax_rows(__hip_bfloat16* __restrict__ Sc)
{
    __hip_bfloat16* p = Sc + (long)blockIdx.x * S;
    const int t = threadIdx.x;
    const int wave = t >> 6, lane = t & 63;
    __shared__ float wred[4], wsum[4];

    u16x8 u = ((const u16x8*)p)[t];
    float v[8];
    float mx = -1e30f;
    #pragma unroll
    for (int j = 0; j < 8; j++) {
        const unsigned int b = ((unsigned int)u[j]) << 16;
        v[j] = __builtin_bit_cast(float, b);
        mx = fmaxf(mx, v[j]);
    }
    #pragma unroll
    for (int off = 32; off; off >>= 1) mx = fmaxf(mx, __shfl_down(mx, off));
    if (lane == 0) wred[wave] = mx;
    __syncthreads();
    mx = fmaxf(fmaxf(wred[0], wred[1]), fmaxf(wred[2], wred[3]));

    float sum = 0.f;
    #pragma unroll
    for (int j = 0; j < 8; j++) { v[j] = expf(v[j] - mx); sum += v[j]; }
    #pragma unroll
    for (int off = 32; off; off >>= 1) sum += __shfl_down(sum, off);
    if (lane == 0) wsum[wave] = sum;
    __syncthreads();
    sum = wsum[0] + wsum[1] + wsum[2] + wsum[3];

    const float inv = 1.f / sum;
    u16x8 o;
    #pragma unroll
    for (int j = 0; j < 8; j++) {
        const __hip_bfloat16 h = __float2bfloat16(v[j] * inv);
        o[j] = __builtin_bit_cast(unsigned short, h);
    }
    ((u16x8*)p)[t] = o;
}

// ---------------------------------------------------------------------------
// z = pvp[0..3] + xf ; accumulate global sum & sumsq into stats (pre-zeroed)
// ---------------------------------------------------------------------------
__global__ __launch_bounds__(256) void attn_reduce(
    const float* __restrict__ pvp, const float* __restrict__ xf,
    float* __restrict__ z, float* __restrict__ stats)
{
    const long SD = (long)S * D;
    const long i0 = (long)blockIdx.x * 2048 + threadIdx.x;
    float s = 0.f, s2 = 0.f;
    #pragma unroll
    for (int j = 0; j < 8; j++) {
        const long i = i0 + j * 256;
        const float v = pvp[i] + pvp[i + SD] + pvp[i + 2 * SD] + pvp[i + 3 * SD]
                        + xf[i];
        z[i] = v;
        s += v; s2 += v * v;
    }
    #pragma unroll
    for (int off = 32; off; off >>= 1) { s += __shfl_down(s, off); s2 += __shfl_down(s2, off); }
    const int wave = threadIdx.x >> 6, lane = threadIdx.x & 63;
    __shared__ float ws1[4], ws2[4];
    if (lane == 0) { ws1[wave] = s; ws2[wave] = s2; }
    __syncthreads();
    if (threadIdx.x == 0) {
        atomicAdd(&stats[0], ws1[0] + ws1[1] + ws1[2] + ws1[3]);
        atomicAdd(&stats[1], ws2[0] + ws2[1] + ws2[2] + ws2[3]);
    }
}

// zn = (z - mean) * rsqrt(var + eps), cast to bf16
__global__ __launch_bounds__(256) void ln_cast(
    const float* __restrict__ z, const float* __restrict__ stats,
    __hip_bfloat16* __restrict__ zn)
{
    const float invN = 1.f / (float)(S * D);
    const float mean = stats[0] * invN;
    const float var  = stats[1] * invN - mean * mean;
    const float rs   = rsqrtf(var + EPS);
    const long i0 = (long)blockIdx.x * 2048 + threadIdx.x;
    #pragma unroll
    for (int j = 0; j < 8; j++) {
        const long i = i0 + j * 256;
        zn[i] = __float2bfloat16((z[i] - mean) * rs);
    }
}

// out = ffp[0..3] + b2[col]
__global__ __launch_bounds__(256) void ff2_reduce(
    const float* __restrict__ ffp, const float* __restrict__ b2,
    float* __restrict__ out)
{
    const long SD = (long)S * D;
    const long i0 = (long)blockIdx.x * 2048 + threadIdx.x;
    #pragma unroll
    for (int j = 0; j < 8; j++) {
        const long i = i0 + j * 256;
        out[i] = ffp[i] + ffp[i + SD] + ffp[i + 2 * SD] + ffp[i + 3 * SD]
                 + b2[i & (D - 1)];
    }
}

// ---------------------------------------------------------------------------
extern "C" void kernel_launch(void* const* d_in, const int* in_sizes, int n_in,
                              void* d_out, int out_size, void* d_ws, size_t ws_size,
                              hipStream_t stream)
{
    const int*   tokens = (const int*)  d_in[0];
    const float* emb    = (const float*)d_in[1];
    const float* Wq     = (const float*)d_in[2];
    const float* bq     = (const float*)d_in[3];
    const float* Wk     = (const float*)d_in[4];
    const float* bk     = (const float*)d_in[5];
    const float* Wv     = (const float*)d_in[6];
    const float* bv     = (const float*)d_in[7];
    const float* W1     = (const float*)d_in[8];
    const float* b1     = (const float*)d_in[9];
    const float* W2     = (const float*)d_in[10];
    const float* b2     = (const float*)d_in[11];
    float* out = (float*)d_out;

    char* w = (char*)d_ws;
    const long MB = 1 << 20;
    // layout with aliasing (peak 168 MB, proven available in round 2/3):
    //  phase         live buffers
    //  embed/casts:  XB@0(4) XF@4(8) W1T@12(6) W2T@18(6) WQT@24(16) WKT@40(16)
    //                WVT@152(16)
    //  QK proj:      + QK@88(64)                         [WQT/WKT dead after]
    //  QKT/softmax:  SC@24(64) over dead WQT/WKT/(gap)   [QK dead after]
    //  VT proj:      VT@88(32) over dead QK              [XB, WVT dead after]
    //  PV:           PVP@120(32) over dead QK tail       [SC, VT dead after]
    //  reduce/LN:    Z@152(8) over dead WVT; ZN@0(4) over dead XB
    //  FF1:          FFH@24(12) over dead SC
    //  FF2:          FF2P@40(32)
    __hip_bfloat16* XB   = (__hip_bfloat16*)(w + 0 * MB);
    float*          XF   = (float*)(w + 4 * MB);
    __hip_bfloat16* W1T  = (__hip_bfloat16*)(w + 12 * MB);
    __hip_bfloat16* W2T  = (__hip_bfloat16*)(w + 18 * MB);
    __hip_bfloat16* WQT  = (__hip_bfloat16*)(w + 24 * MB);  // contiguous w/ WKT
    __hip_bfloat16* WKT  = (__hip_bfloat16*)(w + 40 * MB);
    __hip_bfloat16* SC   = (__hip_bfloat16*)(w + 24 * MB);  // [H][S][S]
    __hip_bfloat16* QK   = (__hip_bfloat16*)(w + 88 * MB);  // [S, 2*HD]
    __hip_bfloat16* VT   = (__hip_bfloat16*)(w + 88 * MB);  // [H][D][S] (after QK dead)
    float*          PVP  = (float*)(w + 120 * MB);          // [4][S][D]
    __hip_bfloat16* WVT  = (__hip_bfloat16*)(w + 152 * MB);
    float*          Z    = (float*)(w + 152 * MB);          // after WVT dead
    __hip_bfloat16* ZN   = (__hip_bfloat16*)(w + 0 * MB);   // after XB dead
    __hip_bfloat16* FFH  = (__hip_bfloat16*)(w + 24 * MB);  // after SC dead
    float*          FF2P = (float*)(w + 40 * MB);           // [4][S][D]
    float*          STATS = (float*)(w + 168 * MB);
    float*          BQK   = (float*)(w + 168 * MB + 4096);  // bq || bk

    hipMemsetAsync(STATS, 0, 256, stream);

    embed_pos<<<S, 256, 0, stream>>>(tokens, emb, XF, XB);

    // weight transpose+cast
    transpose_cast<<<dim3(32, 32, H), 256, 0, stream>>>(Wq, WQT, D, D);
    transpose_cast<<<dim3(32, 32, H), 256, 0, stream>>>(Wk, WKT, D, D);
    transpose_cast<<<dim3(32, 32, H), 256, 0, stream>>>(Wv, WVT, D, D);
    transpose_cast<<<dim3(96, 32, 1), 256, 0, stream>>>(W1, W1T, D, DFF);  // -> [DFF,D]
    transpose_cast<<<dim3(32, 96, 1), 256, 0, stream>>>(W2, W2T, DFF, D);  // -> [D,DFF]
    concat_bias<<<2 * HD / 256, 256, 0, stream>>>(bq, bk, BQK);

    const float inv_sqrt_d = 0.03125f;  // 1/sqrt(1024)

    // Q||K = x @ [Wq;Wk]^T + [bq;bk]   [S, 16384]
    gemm_bt<<<dim3(2 * HD / 128, S / 128), 256, 0, stream>>>(
        XB, WQT, QK, BQK, S, 2 * HD, D, D, D, 2 * HD,
        0, 0, 0, 0,  1, 0, 0, 0,  1, 0, 0,  1.f, F_OUT_BF16 | F_BIAS_COL);

    // SC[h] = Q_h K_h^T / sqrt(D)   [H][S,S] bf16, all heads in one dispatch
    gemm_bt<<<dim3(S / 128, S / 128, H), 256, 0, stream>>>(
        QK, QK + HD, SC, (const float*)nullptr, S, S, D, 2 * HD, 2 * HD, S,
        D, D, (long)S * S, 0,  1, 0, 0, 0,  1, 0, 0,  inv_sqrt_d, F_OUT_BF16);

    softmax_rows<<<H * S, 256, 0, stream>>>(SC);

    // VT[h] = Wv[h]^T @ x^T + bv[h]   [H][D,S]  (QK now dead; VT overlays it)
    gemm_bt<<<dim3(S / 128, D / 128, H), 256, 0, stream>>>(
        WVT, XB, VT, bv, D, S, D, D, D, S,
        (long)D * D, 0, (long)D * S, D,  1, 0, 0, 0,  1, 0, 0,  1.f,
        F_OUT_BF16 | F_BIAS_ROW);

    // PVP[kz] = sum over heads {2kz, 2kz+1} of P_h @ V_h   [4][S,D] fp32,
    // streaming stores (no atomics); each block runs 2 heads x K=2048.
    gemm_bt<<<dim3(D / 128, S / 128, 4), 256, 0, stream>>>(
        SC, VT, PVP, (const float*)nullptr, S, D, S, S, S, D,
        0, 0, 0, 0,
        4, (long)2 * S * S, (long)2 * D * S, (long)S * D,
        2, (long)S * S, (long)D * S,
        1.f, 0);

    attn_reduce<<<(S * D) / 2048, 256, 0, stream>>>(PVP, XF, Z, STATS);
    ln_cast<<<(S * D) / 2048, 256, 0, stream>>>(Z, STATS, ZN);

    // FF1: relu(zn @ W1 + b1)  [S,DFF] bf16
    gemm_bt<<<dim3(DFF / 128, S / 128), 256, 0, stream>>>(
        ZN, W1T, FFH, b1, S, DFF, D, D, D, DFF,
        0, 0, 0, 0,  1, 0, 0, 0,  1, 0, 0,  1.f,
        F_OUT_BF16 | F_BIAS_COL | F_RELU);

    // FF2 partials: FF2P[kz] = h[:, kz*768:(kz+1)*768] @ W2T slice  [4][S,D]
    gemm_bt<<<dim3(D / 128, S / 128, 4), 256, 0, stream>>>(
        FFH, W2T, FF2P, (const float*)nullptr, S, D, DFF / 4, DFF, DFF, D,
        0, 0, 0, 0,
        4, (long)DFF / 4, (long)DFF / 4, (long)S * D,
        1, 0, 0,
        1.f, 0);

    ff2_reduce<<<(S * D) / 2048, 256, 0, stream>>>(FF2P, b2, out);
}

// Round 5
// 716.796 us; speedup vs baseline: 1.3370x; 1.0777x over previous
//
#include <hip/hip_runtime.h>
#include <hip/hip_bf16.h>

#define D 1024
#define H 8
#define S 2048
#define DFF 3072
#define HD 8192
#define EPS 1e-5f

typedef __attribute__((ext_vector_type(8))) short short8;   // 8 bf16 in 4 VGPRs
typedef __attribute__((ext_vector_type(4))) float float4v;  // MFMA acc
typedef __attribute__((ext_vector_type(8))) unsigned short u16x8;

// GEMM flags
#define F_OUT_BF16 1
#define F_RELU     4
#define F_BIAS_COL 8
#define F_BIAS_ROW 16

__device__ __forceinline__ void async16(void* lds, const void* g) {
    __builtin_amdgcn_global_load_lds(
        (const __attribute__((address_space(1))) unsigned int*)g,
        (__attribute__((address_space(3))) unsigned int*)lds, 16, 0, 0);
}

// ---------------------------------------------------------------------------
// C = alpha * A.Bt^T (+bias)(+relu).  A:[M,K] bf16 lda; Bt:[N,K] bf16 ldb.
// blockIdx.z = z2 * kSplit + kz:
//   z2 batches with strides sA/sB/sC/sBias;
//   kz K-splits with strides sAz/sBz/sCz (each kz writes its OWN C slice).
// nkb batch-K chunks per block (advance sAk/sBk between chunks) accumulate
// in registers. Block 256 = 4 waves 2x2; wave 64x64 via 4x4 mfma_16x16x32.
// BK=64: 32 MFMA per barrier pair. K % 64 == 0 required.
// LDS swizzle: slot(r,c) = r*8 + (c ^ (r&7)); 16B chunks; conflict-floor
// reads; staging source offset (t&7)^((t>>3)&7) invariant across a thread's
// 4 slots (rows r0+32i, 32i = 0 mod 8).
// ---------------------------------------------------------------------------
__global__ __launch_bounds__(256) void gemm_bt(
    const __hip_bfloat16* __restrict__ A,
    const __hip_bfloat16* __restrict__ Bt,
    void* __restrict__ Cout,
    const float* __restrict__ bias,
    int M, int N, int K,
    int lda, int ldb, int ldc,
    long sA, long sB, long sC, int sBias,
    int kSplit, long sAz, long sBz, long sCz,
    int nkb, long sAk, long sBk,
    float alpha, int flags)
{
    __shared__ __align__(16) __hip_bfloat16 As[128 * 64];
    __shared__ __align__(16) __hip_bfloat16 Bs[128 * 64];

    const int z  = blockIdx.z;
    const int z2 = z / kSplit;
    const int kz = z - z2 * kSplit;
    A  += (long)z2 * sA + (long)kz * sAz;
    Bt += (long)z2 * sB + (long)kz * sBz;
    const float* bp = bias ? bias + (long)z2 * sBias : nullptr;

    // XCD-aware tile swizzle: blocks i -> XCD i%8; contiguous tile range per
    // XCD, band-mapped (4 cols wide) for a square-ish L2 working set.
    const int nn = gridDim.x, nm = gridDim.y;
    const int tot = nm * nn;
    const int pid = blockIdx.y * nn + blockIdx.x;
    const int lin = (pid & 7) * (tot >> 3) + (pid >> 3);
    const int bandh = nm << 2;
    const int band = lin / bandh;
    const int rr = lin - band * bandh;
    const int m0 = (rr >> 2) * 128;
    const int n0 = (band * 4 + (rr & 3)) * 128;

    const int t    = threadIdx.x;
    const int wave = t >> 6;
    const int lane = t & 63;
    const int lr   = lane & 15;     // row within 16x16 fragment
    const int lq   = lane >> 4;     // k-quad
    const int lqx0 = lq ^ (lr & 7); // swizzled chunk, k-half 0
    const int wm   = (wave >> 1) * 64;
    const int wn   = (wave & 1) * 64;

    // staging: tile = 128 rows x 8 chunks(16B) = 1024 slots; thread t owns
    // slots t+256*i (lane-contiguous dest required by global_load_lds).
    const int r0 = t >> 3;
    const int kc = (t & 7) ^ ((t >> 3) & 7);
    const __hip_bfloat16* Ap[4];
    const __hip_bfloat16* Bp[4];
    uint4* dA[4];
    uint4* dB[4];
    #pragma unroll
    for (int i = 0; i < 4; i++) {
        Ap[i] = A  + (long)(m0 + r0 + 32 * i) * lda + kc * 8;
        Bp[i] = Bt + (long)(n0 + r0 + 32 * i) * ldb + kc * 8;
        dA[i] = (uint4*)As + t + 256 * i;
        dB[i] = (uint4*)Bs + t + 256 * i;
    }

    float4v acc[4][4];
    const float4v vzero = {0.f, 0.f, 0.f, 0.f};
    #pragma unroll
    for (int i = 0; i < 4; i++)
        #pragma unroll
        for (int j = 0; j < 4; j++) acc[i][j] = vzero;

    for (int kb = 0; kb < nkb; kb++) {
        for (int k0 = 0; k0 < K; k0 += 64) {
            __syncthreads();            // prev iter's ds_reads complete
            #pragma unroll
            for (int i = 0; i < 4; i++) async16(dA[i], Ap[i]);
            #pragma unroll
            for (int i = 0; i < 4; i++) async16(dB[i], Bp[i]);
            #pragma unroll
            for (int i = 0; i < 4; i++) { Ap[i] += 64; Bp[i] += 64; }
            __syncthreads();            // vmcnt(0) drain: tiles ready

            short8 af[4], bf[4];
            // k-half 0
            #pragma unroll
            for (int i = 0; i < 4; i++)
                af[i] = *(const short8*)&As[(wm + i * 16 + lr) * 64 + lqx0 * 8];
            #pragma unroll
            for (int i = 0; i < 4; i++)
                bf[i] = *(const short8*)&Bs[(wn + i * 16 + lr) * 64 + lqx0 * 8];
            #pragma unroll
            for (int mi = 0; mi < 4; mi++)
                #pragma unroll
                for (int ni = 0; ni < 4; ni++)
                    acc[mi][ni] = __builtin_amdgcn_mfma_f32_16x16x32_bf16(
                        af[mi], bf[ni], acc[mi][ni], 0, 0, 0);
            // k-half 1 (chunk index ^4)
            #pragma unroll
            for (int i = 0; i < 4; i++)
                af[i] = *(const short8*)&As[(wm + i * 16 + lr) * 64 + (lqx0 ^ 4) * 8];
            #pragma unroll
            for (int i = 0; i < 4; i++)
                bf[i] = *(const short8*)&Bs[(wn + i * 16 + lr) * 64 + (lqx0 ^ 4) * 8];
            #pragma unroll
            for (int mi = 0; mi < 4; mi++)
                #pragma unroll
                for (int ni = 0; ni < 4; ni++)
                    acc[mi][ni] = __builtin_amdgcn_mfma_f32_16x16x32_bf16(
                        af[mi], bf[ni], acc[mi][ni], 0, 0, 0);
        }
        #pragma unroll
        for (int i = 0; i < 4; i++) {
            Ap[i] += sAk - K;
            Bp[i] += sBk - K;
        }
    }

    __hip_bfloat16* Cb = (__hip_bfloat16*)Cout + (long)z2 * sC + (long)kz * sCz;
    float*          Cf = (float*)Cout          + (long)z2 * sC + (long)kz * sCz;

    // epilogue: lane, reg r -> row = 4*lq + r, col = lr (within 16x16 tile)
    #pragma unroll
    for (int mi = 0; mi < 4; mi++) {
        #pragma unroll
        for (int r = 0; r < 4; r++) {
            const int row = m0 + wm + mi * 16 + lq * 4 + r;
            const float brow = (bp && (flags & F_BIAS_ROW)) ? bp[row] : 0.f;
            #pragma unroll
            for (int ni = 0; ni < 4; ni++) {
                const int col = n0 + wn + ni * 16 + lr;
                float v = acc[mi][ni][r] * alpha + brow;
                if (bp && (flags & F_BIAS_COL)) v += bp[col];
                if (flags & F_RELU) v = fmaxf(v, 0.f);
                const long idx = (long)row * ldc + col;
                if (flags & F_OUT_BF16) Cb[idx] = __float2bfloat16(v);
                else                    Cf[idx] = v;
            }
        }
    }
}

// ---------------------------------------------------------------------------
// fp32 [R,C] -> bf16 [C,R] transpose+cast, batched via blockIdx.z
// ---------------------------------------------------------------------------
__global__ __launch_bounds__(256) void transpose_cast(
    const float* __restrict__ in, __hip_bfloat16* __restrict__ out, int R, int C)
{
    __shared__ float tile[32][33];
    const long boff = (long)blockIdx.z * R * C;
    const int c0 = blockIdx.x * 32, r0 = blockIdx.y * 32;
    const int tx = threadIdx.x & 31, ty = threadIdx.x >> 5;
    #pragma unroll
    for (int i = ty; i < 32; i += 8)
        tile[i][tx] = in[boff + (long)(r0 + i) * C + c0 + tx];
    __syncthreads();
    #pragma unroll
    for (int i = ty; i < 32; i += 8)
        out[boff + (long)(c0 + i) * R + r0 + tx] = __float2bfloat16(tile[tx][i]);
}

// concat two float vectors of length HD into one of length 2*HD
__global__ __launch_bounds__(256) void concat_bias(
    const float* __restrict__ a, const float* __restrict__ b,
    float* __restrict__ o)
{
    const int i = blockIdx.x * 256 + threadIdx.x;
    o[i] = (i < HD) ? a[i] : b[i - HD];
}

// ---------------------------------------------------------------------------
// x = emb[tokens] + sinusoidal PE ; writes fp32 and bf16 copies
// ---------------------------------------------------------------------------
__global__ __launch_bounds__(256) void embed_pos(
    const int* __restrict__ tokens, const float* __restrict__ emb,
    float* __restrict__ xf, __hip_bfloat16* __restrict__ xb)
{
    const int s = blockIdx.x;
    const int tok = tokens[s];
    for (int d = threadIdx.x; d < D; d += 256) {
        const float e = emb[(long)tok * D + d];
        const float expo = (float)((d >> 1) << 1) / (float)D;
        const float angle = (float)s * powf(10000.f, -expo);
        const float pe = (d & 1) ? cosf(angle) : sinf(angle);
        const float v = e + pe;
        xf[(long)s * D + d] = v;
        xb[(long)s * D + d] = __float2bfloat16(v);
    }
}

// ---------------------------------------------------------------------------
// in-place row softmax over bf16 [rows, S]; one block per row (vectorized)
// ---------------------------------------------------------------------------
__global__ __launch_bounds__(256) void softmax_rows(__hip_bfloat16* __restrict__ Sc)
{
    __hip_bfloat16* p = Sc + (long)blockIdx.x * S;
    const int t = threadIdx.x;
    const int wave = t >> 6, lane = t & 63;
    __shared__ float wred[4], wsum[4];

    u16x8 u = ((const u16x8*)p)[t];
    float v[8];
    float mx = -1e30f;
    #pragma unroll
    for (int j = 0; j < 8; j++) {
        const unsigned int b = ((unsigned int)u[j]) << 16;
        v[j] = __builtin_bit_cast(float, b);
        mx = fmaxf(mx, v[j]);
    }
    #pragma unroll
    for (int off = 32; off; off >>= 1) mx = fmaxf(mx, __shfl_down(mx, off));
    if (lane == 0) wred[wave] = mx;
    __syncthreads();
    mx = fmaxf(fmaxf(wred[0], wred[1]), fmaxf(wred[2], wred[3]));

    float sum = 0.f;
    #pragma unroll
    for (int j = 0; j < 8; j++) { v[j] = expf(v[j] - mx); sum += v[j]; }
    #pragma unroll
    for (int off = 32; off; off >>= 1) sum += __shfl_down(sum, off);
    if (lane == 0) wsum[wave] = sum;
    __syncthreads();
    sum = wsum[0] + wsum[1] + wsum[2] + wsum[3];

    const float inv = 1.f / sum;
    u16x8 o;
    #pragma unroll
    for (int j = 0; j < 8; j++) {
        const __hip_bfloat16 h = __float2bfloat16(v[j] * inv);
        o[j] = __builtin_bit_cast(unsigned short, h);
    }
    ((u16x8*)p)[t] = o;
}

// ---------------------------------------------------------------------------
// z = sum of 8 bf16 PV slices + xf ; global sum/sumsq into stats (pre-zeroed)
// ---------------------------------------------------------------------------
__global__ __launch_bounds__(256) void attn_reduce(
    const __hip_bfloat16* __restrict__ pvb, const float* __restrict__ xf,
    float* __restrict__ z, float* __restrict__ stats)
{
    const long SD = (long)S * D;
    const long i0 = (long)blockIdx.x * 2048 + threadIdx.x * 8;
    float s = 0.f, s2 = 0.f;
    float v[8];
    {
        const float4* x4 = (const float4*)(xf + i0);
        #pragma unroll
        for (int j = 0; j < 2; j++) {
            const float4 x = x4[j];
            v[j * 4 + 0] = x.x; v[j * 4 + 1] = x.y;
            v[j * 4 + 2] = x.z; v[j * 4 + 3] = x.w;
        }
    }
    #pragma unroll
    for (int sl = 0; sl < H; sl++) {
        const u16x8 u = *(const u16x8*)(pvb + sl * SD + i0);
        #pragma unroll
        for (int j = 0; j < 8; j++) {
            const unsigned int b = ((unsigned int)u[j]) << 16;
            v[j] += __builtin_bit_cast(float, b);
        }
    }
    float4* z4 = (float4*)(z + i0);
    #pragma unroll
    for (int j = 0; j < 2; j++) {
        float4 o;
        o.x = v[j * 4 + 0]; o.y = v[j * 4 + 1];
        o.z = v[j * 4 + 2]; o.w = v[j * 4 + 3];
        z4[j] = o;
    }
    #pragma unroll
    for (int j = 0; j < 8; j++) { s += v[j]; s2 += v[j] * v[j]; }
    #pragma unroll
    for (int off = 32; off; off >>= 1) { s += __shfl_down(s, off); s2 += __shfl_down(s2, off); }
    const int wave = threadIdx.x >> 6, lane = threadIdx.x & 63;
    __shared__ float ws1[4], ws2[4];
    if (lane == 0) { ws1[wave] = s; ws2[wave] = s2; }
    __syncthreads();
    if (threadIdx.x == 0) {
        atomicAdd(&stats[0], ws1[0] + ws1[1] + ws1[2] + ws1[3]);
        atomicAdd(&stats[1], ws2[0] + ws2[1] + ws2[2] + ws2[3]);
    }
}

// zn = (z - mean) * rsqrt(var + eps), cast to bf16
__global__ __launch_bounds__(256) void ln_cast(
    const float* __restrict__ z, const float* __restrict__ stats,
    __hip_bfloat16* __restrict__ zn)
{
    const float invN = 1.f / (float)(S * D);
    const float mean = stats[0] * invN;
    const float var  = stats[1] * invN - mean * mean;
    const float rs   = rsqrtf(var + EPS);
    const long i0 = (long)blockIdx.x * 2048 + threadIdx.x;
    #pragma unroll
    for (int j = 0; j < 8; j++) {
        const long i = i0 + j * 256;
        zn[i] = __float2bfloat16((z[i] - mean) * rs);
    }
}

// out = ffp[0..3] + b2[col]
__global__ __launch_bounds__(256) void ff2_reduce(
    const float* __restrict__ ffp, const float* __restrict__ b2,
    float* __restrict__ out)
{
    const long SD = (long)S * D;
    const long i0 = (long)blockIdx.x * 2048 + threadIdx.x;
    #pragma unroll
    for (int j = 0; j < 8; j++) {
        const long i = i0 + j * 256;
        out[i] = ffp[i] + ffp[i + SD] + ffp[i + 2 * SD] + ffp[i + 3 * SD]
                 + b2[i & (D - 1)];
    }
}

// ---------------------------------------------------------------------------
extern "C" void kernel_launch(void* const* d_in, const int* in_sizes, int n_in,
                              void* d_out, int out_size, void* d_ws, size_t ws_size,
                              hipStream_t stream)
{
    const int*   tokens = (const int*)  d_in[0];
    const float* emb    = (const float*)d_in[1];
    const float* Wq     = (const float*)d_in[2];
    const float* bq     = (const float*)d_in[3];
    const float* Wk     = (const float*)d_in[4];
    const float* bk     = (const float*)d_in[5];
    const float* Wv     = (const float*)d_in[6];
    const float* bv     = (const float*)d_in[7];
    const float* W1     = (const float*)d_in[8];
    const float* b1     = (const float*)d_in[9];
    const float* W2     = (const float*)d_in[10];
    const float* b2     = (const float*)d_in[11];
    float* out = (float*)d_out;

    char* w = (char*)d_ws;
    const long MB = 1 << 20;
    // layout with aliasing (peak 168 MB):
    //  XB@0(4) XF@4(8) W1T@12(6) W2T@18(6) WQT@24(16) WKT@40(16) WVT@152(16)
    //  QK@88(64) -> SC@24(64) over dead WQT/WKT -> VT@88(32) over dead QK
    //  PVB@120(32, bf16 8 slices) | Z@152(8) over dead WVT | ZN@0(4) over XB
    //  FFH@24(12) over dead SC | FF2P@40(32)
    __hip_bfloat16* XB   = (__hip_bfloat16*)(w + 0 * MB);
    float*          XF   = (float*)(w + 4 * MB);
    __hip_bfloat16* W1T  = (__hip_bfloat16*)(w + 12 * MB);
    __hip_bfloat16* W2T  = (__hip_bfloat16*)(w + 18 * MB);
    __hip_bfloat16* WQT  = (__hip_bfloat16*)(w + 24 * MB);  // contiguous w/ WKT
    __hip_bfloat16* WKT  = (__hip_bfloat16*)(w + 40 * MB);
    __hip_bfloat16* SC   = (__hip_bfloat16*)(w + 24 * MB);  // [H][S][S]
    __hip_bfloat16* QK   = (__hip_bfloat16*)(w + 88 * MB);  // [S, 2*HD]
    __hip_bfloat16* VT   = (__hip_bfloat16*)(w + 88 * MB);  // [H][D][S]
    __hip_bfloat16* PVB  = (__hip_bfloat16*)(w + 120 * MB); // [8][S][D] bf16
    __hip_bfloat16* WVT  = (__hip_bfloat16*)(w + 152 * MB);
    float*          Z    = (float*)(w + 152 * MB);          // after WVT dead
    __hip_bfloat16* ZN   = (__hip_bfloat16*)(w + 0 * MB);   // after XB dead
    __hip_bfloat16* FFH  = (__hip_bfloat16*)(w + 24 * MB);  // after SC dead
    float*          FF2P = (float*)(w + 40 * MB);           // [4][S][D]
    float*          STATS = (float*)(w + 168 * MB);
    float*          BQK   = (float*)(w + 168 * MB + 4096);  // bq || bk

    hipMemsetAsync(STATS, 0, 256, stream);

    embed_pos<<<S, 256, 0, stream>>>(tokens, emb, XF, XB);

    // weight transpose+cast
    transpose_cast<<<dim3(32, 32, H), 256, 0, stream>>>(Wq, WQT, D, D);
    transpose_cast<<<dim3(32, 32, H), 256, 0, stream>>>(Wk, WKT, D, D);
    transpose_cast<<<dim3(32, 32, H), 256, 0, stream>>>(Wv, WVT, D, D);
    transpose_cast<<<dim3(96, 32, 1), 256, 0, stream>>>(W1, W1T, D, DFF);  // -> [DFF,D]
    transpose_cast<<<dim3(32, 96, 1), 256, 0, stream>>>(W2, W2T, DFF, D);  // -> [D,DFF]
    concat_bias<<<2 * HD / 256, 256, 0, stream>>>(bq, bk, BQK);

    const float inv_sqrt_d = 0.03125f;  // 1/sqrt(1024)

    // Q||K = x @ [Wq;Wk]^T + [bq;bk]   [S, 16384]
    gemm_bt<<<dim3(2 * HD / 128, S / 128), 256, 0, stream>>>(
        XB, WQT, QK, BQK, S, 2 * HD, D, D, D, 2 * HD,
        0, 0, 0, 0,  1, 0, 0, 0,  1, 0, 0,  1.f, F_OUT_BF16 | F_BIAS_COL);

    // SC[h] = Q_h K_h^T / sqrt(D)   [H][S,S] bf16, all heads in one dispatch
    gemm_bt<<<dim3(S / 128, S / 128, H), 256, 0, stream>>>(
        QK, QK + HD, SC, (const float*)nullptr, S, S, D, 2 * HD, 2 * HD, S,
        D, D, (long)S * S, 0,  1, 0, 0, 0,  1, 0, 0,  inv_sqrt_d, F_OUT_BF16);

    softmax_rows<<<H * S, 256, 0, stream>>>(SC);

    // VT[h] = Wv[h]^T @ x^T + bv[h]   [H][D,S]  (QK now dead; VT overlays it)
    gemm_bt<<<dim3(S / 128, D / 128, H), 256, 0, stream>>>(
        WVT, XB, VT, bv, D, S, D, D, D, S,
        (long)D * D, 0, (long)D * S, D,  1, 0, 0, 0,  1, 0, 0,  1.f,
        F_OUT_BF16 | F_BIAS_ROW);

    // PVB[h] = P_h @ V_h   [8][S,D] bf16 partial slices, streaming stores;
    // kSplit=8 (one head per slice) -> 1024 blocks, 4/CU.
    gemm_bt<<<dim3(D / 128, S / 128, 8), 256, 0, stream>>>(
        SC, VT, PVB, (const float*)nullptr, S, D, S, S, S, D,
        0, 0, 0, 0,
        8, (long)S * S, (long)D * S, (long)S * D,
        1, 0, 0,
        1.f, F_OUT_BF16);

    attn_reduce<<<(S * D) / 2048, 256, 0, stream>>>(PVB, XF, Z, STATS);
    ln_cast<<<(S * D) / 2048, 256, 0, stream>>>(Z, STATS, ZN);

    // FF1: relu(zn @ W1 + b1)  [S,DFF] bf16
    gemm_bt<<<dim3(DFF / 128, S / 128), 256, 0, stream>>>(
        ZN, W1T, FFH, b1, S, DFF, D, D, D, DFF,
        0, 0, 0, 0,  1, 0, 0, 0,  1, 0, 0,  1.f,
        F_OUT_BF16 | F_BIAS_COL | F_RELU);

    // FF2 partials: FF2P[kz] = h[:, kz*768:(kz+1)*768] @ W2T slice  [4][S,D]
    gemm_bt<<<dim3(D / 128, S / 128, 4), 256, 0, stream>>>(
        FFH, W2T, FF2P, (const float*)nullptr, S, D, DFF / 4, DFF, DFF, D,
        0, 0, 0, 0,
        4, (long)DFF / 4, (long)DFF / 4, (long)S * D,
        1, 0, 0,
        1.f, 0);

    ff2_reduce<<<(S * D) / 2048, 256, 0, stream>>>(FF2P, b2, out);
}